// Round 11
// baseline (184.267 us; speedup 1.0000x reference)
//
#include <hip/hip_runtime.h>

// Problem constants
#define BB 4
#define CC 16
#define HH 256
#define WW 256
#define NN (HH*WW)      // 65536
#define SS 100
#define SPL 5           // s-split: 20 s per wave
#define EPSV 1e-32f

// ws layout (float offsets)
#define PQ_OFF    0u                      // [8 bq][100 s][4 row][17]        = 54400
#define SPFN_OFF  54400u                  // [8 bq][16 c][100 s]             = 12800
#define PFSP_OFF  67200u                  // [4][16][65536]                  = 4194304
#define PPART_OFF PFSP_OFF                // [8][64 win][100 s][4 row][17]   = 3481600
// PPART aliases PFSP: consumed by k_reduceP before k_pass2 overwrites.
// total = 67200 + 4194304 floats = 17.05 MB

__device__ __forceinline__ float dot4(const float4& a, const float4& b) {
    return a.x * b.x + a.y * b.y + a.z * b.z + a.w * b.w;
}
__device__ __forceinline__ float sum4(const float4& a) {
    return a.x + a.y + a.z + a.w;
}
__device__ __forceinline__ void fma2g(float2& a, float c1, const float2& v1,
                                      float c2, const float2& v2) {
    a.x += c1 * v1.x + c2 * v2.x;
    a.y += c1 * v1.y + c2 * v2.y;
}

// DPP lane-combine. MUST be in uniform (wave-level) control flow (R9 lesson).
#define DPPQP(x, ctrl) __int_as_float(__builtin_amdgcn_update_dpp( \
    0, __float_as_int(x), ctrl, 0xF, 0xF, true))
// ctrl: 0xB1 quad_perm xor1; 0x4E quad_perm xor2; 0x114 row_shr:4; 0x118 row_shr:8

// ---------------- pass1 (K1) ----------------
// Wave owns (bq, 1024-px window, 4-channel quad h, 20-s slice).
// pf in 16 float4 regs (4c x 4 positions). Per s: FOUR 1KB coalesced Q loads
// (4 KB), 16 dot4, then ROW-LEVEL reduce only — pure DPP, no DS pipe, no
// cross-row: pair(xor1)+sel -> quad(xor2)+sel -> stripe c=lane&3 ->
// row_shr4 + row_shr8 -> lanes 12-15 of each 16-lane row hold row totals.
// Stores: 16 lanes x 1 float per s (4 rows x 4 channels); qsum on h==0.
#define QLD(X, k) \
    X##0 = *(const float4*)(qptr + (size_t)(k) * NN); \
    X##1 = *(const float4*)(qptr + (size_t)(k) * NN + 256); \
    X##2 = *(const float4*)(qptr + (size_t)(k) * NN + 512); \
    X##3 = *(const float4*)(qptr + (size_t)(k) * NN + 768);

#define P1_STEP(X, sidx) { \
    float t0 = dot4(p00,X##0)+dot4(p01,X##1)+dot4(p02,X##2)+dot4(p03,X##3); \
    float t1 = dot4(p10,X##0)+dot4(p11,X##1)+dot4(p12,X##2)+dot4(p13,X##3); \
    float t2 = dot4(p20,X##0)+dot4(p21,X##1)+dot4(p22,X##2)+dot4(p23,X##3); \
    float t3 = dot4(p30,X##0)+dot4(p31,X##1)+dot4(p32,X##2)+dot4(p33,X##3); \
    t0 += DPPQP(t0,0xB1); t1 += DPPQP(t1,0xB1); \
    t2 += DPPQP(t2,0xB1); t3 += DPPQP(t3,0xB1); \
    float u0 = odd ? t1 : t0; \
    float u1 = odd ? t3 : t2; \
    u0 += DPPQP(u0,0x4E); u1 += DPPQP(u1,0x4E); \
    float w = hi2 ? u1 : u0; \
    w += DPPQP(w,0x114); \
    w += DPPQP(w,0x118); \
    if (h == 0) { \
        float qv = sum4(X##0)+sum4(X##1)+sum4(X##2)+sum4(X##3); \
        qv += DPPQP(qv,0xB1); qv += DPPQP(qv,0x4E); \
        qv += DPPQP(qv,0x114); qv += DPPQP(qv,0x118); \
        if ((lane & 15) == 15) \
            sout[(size_t)(sidx) * 68 + (lane >> 4) * 17 + 16] = qv; \
    } \
    if ((lane & 15) >= 12) \
        sout[(size_t)(sidx) * 68 + (lane >> 4) * 17 + h4 + (lane & 3)] = w; \
}

__global__ __launch_bounds__(256, 2) void k_pass1(const float* __restrict__ pf,
                                                  const float* __restrict__ Q1,
                                                  const float* __restrict__ Q2,
                                                  float* __restrict__ ws) {
    int tid = threadIdx.x, wid = tid >> 6, lane = tid & 63;
    int W = blockIdx.x * 4 + wid;       // 0..10239, task = (((bq*64+win)*5+sp)*4+h)
    int h  = W & 3;                     // channel quad (block shares (bq,win,sp))
    int t1i = W >> 2;
    int sp  = t1i % 5;
    int t2i = t1i / 5;
    int win = t2i & 63;
    int bq  = t2i >> 6;
    int b = bq >> 1, q = bq & 1;
    bool odd = lane & 1;
    bool hi2 = lane & 2;
    int h4 = h * 4;

    int nbase = win * 1024 + lane * 4;
    const float* qptr = (q ? Q2 : Q1) + (size_t)b * SS * NN
                        + (size_t)(sp * 20) * NN + nbase;
    const float* PF   = pf + (size_t)b * CC * NN + (size_t)h4 * NN + nbase;

    // pf: 4 channels x 4 positions, persistent in registers (64 VGPR)
    float4 p00 = *(const float4*)(PF + (size_t)0 * NN);
    float4 p01 = *(const float4*)(PF + (size_t)0 * NN + 256);
    float4 p02 = *(const float4*)(PF + (size_t)0 * NN + 512);
    float4 p03 = *(const float4*)(PF + (size_t)0 * NN + 768);
    float4 p10 = *(const float4*)(PF + (size_t)1 * NN);
    float4 p11 = *(const float4*)(PF + (size_t)1 * NN + 256);
    float4 p12 = *(const float4*)(PF + (size_t)1 * NN + 512);
    float4 p13 = *(const float4*)(PF + (size_t)1 * NN + 768);
    float4 p20 = *(const float4*)(PF + (size_t)2 * NN);
    float4 p21 = *(const float4*)(PF + (size_t)2 * NN + 256);
    float4 p22 = *(const float4*)(PF + (size_t)2 * NN + 512);
    float4 p23 = *(const float4*)(PF + (size_t)2 * NN + 768);
    float4 p30 = *(const float4*)(PF + (size_t)3 * NN);
    float4 p31 = *(const float4*)(PF + (size_t)3 * NN + 256);
    float4 p32 = *(const float4*)(PF + (size_t)3 * NN + 512);
    float4 p33 = *(const float4*)(PF + (size_t)3 * NN + 768);

    float* sout = ws + PPART_OFF
                + (size_t)((bq * 64 + win) * 100 + sp * 20) * 68;

    float4 A0, A1, A2, A3, B0, B1, B2, B3;
    QLD(A, 0)
    for (int s = 0; s < 18; s += 2) {
        QLD(B, s + 1)
        P1_STEP(A, s)
        QLD(A, s + 2)
        P1_STEP(B, s + 1)
    }
    QLD(B, 19)
    P1_STEP(A, 18)
    P1_STEP(B, 19)
}

// ---------------- K2: reduce over 64 windows ----------------
// PQ[bq][sg][row][c] = sum_win PPART[bq][win][sg][row][c]
__global__ __launch_bounds__(256) void k_reduceP(float* __restrict__ ws) {
    int sgc = blockIdx.x;  // 0..9 (10 s each)
    int bq  = blockIdx.y;  // 0..7
    int tid = threadIdx.x;
    for (int o = tid; o < 680; o += 256) {
        int sl = o / 68, slot = o % 68;
        int sg = sgc * 10 + sl;
        const float* pp = ws + PPART_OFF + (size_t)(bq * 64) * 6800
                        + (size_t)sg * 68 + slot;
        float a0 = 0.f, a1 = 0.f, a2 = 0.f, a3 = 0.f;
        #pragma unroll 4
        for (int win = 0; win < 64; win += 4) {
            a0 += pp[(size_t)(win + 0) * 6800];
            a1 += pp[(size_t)(win + 1) * 6800];
            a2 += pp[(size_t)(win + 2) * 6800];
            a3 += pp[(size_t)(win + 3) * 6800];
        }
        ws[PQ_OFF + (size_t)(bq * 100 + sg) * 68 + slot] = (a0 + a1) + (a2 + a3);
    }
}

// ---------------- K3: rels + finalize ----------------
// PQ slot layout [s][4 row][17]; sum the 4 rows here.
__global__ __launch_bounds__(256) void k_finalize(const float* __restrict__ spf1,
                                                  const float* __restrict__ spf2,
                                                  float* __restrict__ ws) {
    int bq = blockIdx.x;  // 0..7
    int b = bq >> 1, q = bq & 1;
    __shared__ float sp[CC][SS];
    __shared__ float rl[SS][SS + 1];
    __shared__ float Pl[CC * SS];
    __shared__ float qs[SS];
    __shared__ float den[SS];
    int tid = threadIdx.x;

    const float* spf = (q ? spf2 : spf1) + (size_t)b * CC * SS;
    for (int i = tid; i < CC * SS; i += 256) sp[i / SS][i % SS] = spf[i];
    __syncthreads();
    for (int i = tid; i < SS * SS; i += 256) {
        int s = i / SS, t = i % SS;
        float d2 = 0.f;
        #pragma unroll
        for (int c = 0; c < CC; ++c) {
            float d = sp[c][t] - sp[c][s];
            d2 += d * d;
        }
        rl[s][t] = expf(-d2);
    }
    const float* pq = ws + PQ_OFF + (size_t)bq * 100 * 68;
    for (int idx = tid; idx < CC * SS; idx += 256) {
        int c = idx / SS, s = idx % SS;
        const float* p = pq + (size_t)s * 68 + c;
        Pl[idx] = (p[0] + p[17]) + (p[34] + p[51]);
    }
    if (tid < SS) {
        const float* p = pq + (size_t)tid * 68 + 16;
        qs[tid] = (p[0] + p[17]) + (p[34] + p[51]);
    }
    __syncthreads();
    if (tid < SS) {
        float a = 0.f;
        for (int t = 0; t < SS; ++t) a += rl[tid][t] * qs[t];
        den[tid] = a + EPSV;
    }
    __syncthreads();
    float* sout = ws + SPFN_OFF + (size_t)bq * CC * SS;
    for (int idx = tid; idx < CC * SS; idx += 256) {
        int c = idx / SS, s = idx % SS;
        float a = 0.f;
        for (int t = 0; t < SS; ++t) a += rl[s][t] * Pl[c * SS + t];
        sout[idx] = a / den[s];
    }
}

// ---------------- K4: pf_sp = spf1n@Q1 + spf2n@Q2 ---------------- (unchanged)
#define P2FMA(X, s) { \
    _Pragma("unroll") for (int g = 0; g < 4; ++g) { \
        float4 s1 = *(const float4*)&sp[0][s][g * 4]; \
        float4 s2 = *(const float4*)&sp[1][s][g * 4]; \
        fma2g(acc[g*4+0], s1.x, X##1, s2.x, X##2); \
        fma2g(acc[g*4+1], s1.y, X##1, s2.y, X##2); \
        fma2g(acc[g*4+2], s1.z, X##1, s2.z, X##2); \
        fma2g(acc[g*4+3], s1.w, X##1, s2.w, X##2); } }

__global__ __launch_bounds__(128) void k_pass2(const float* __restrict__ Q1,
                                               const float* __restrict__ Q2,
                                               float* __restrict__ ws) {
    int blk = blockIdx.x;   // 0..255
    int b   = blockIdx.y;
    __shared__ float sp[2][SS][CC];
    int tid = threadIdx.x;
    const float* spin = ws + SPFN_OFF + (size_t)b * 2 * CC * SS;
    for (int idx = tid; idx < 2 * CC * SS; idx += 128) {
        int qq = idx / (CC * SS), rem = idx % (CC * SS);
        int c = rem / SS, s = rem % SS;
        sp[qq][s][c] = spin[idx];
    }
    __syncthreads();
    int n = blk * 256 + tid * 2;
    const float* q1p = Q1 + (size_t)b * SS * NN + n;
    const float* q2p = Q2 + (size_t)b * SS * NN + n;
    float2 acc[CC];
    #pragma unroll
    for (int c = 0; c < CC; ++c) acc[c] = make_float2(0.f, 0.f);
    float2 A1, A2, B1, B2;
    A1 = *(const float2*)(q1p);
    A2 = *(const float2*)(q2p);
    #pragma unroll 2
    for (int s = 0; s < 98; s += 2) {
        B1 = *(const float2*)(q1p + (size_t)(s + 1) * NN);
        B2 = *(const float2*)(q2p + (size_t)(s + 1) * NN);
        P2FMA(A, s)
        A1 = *(const float2*)(q1p + (size_t)(s + 2) * NN);
        A2 = *(const float2*)(q2p + (size_t)(s + 2) * NN);
        P2FMA(B, s + 1)
    }
    B1 = *(const float2*)(q1p + (size_t)99 * NN);
    B2 = *(const float2*)(q2p + (size_t)99 * NN);
    P2FMA(A, 98)
    P2FMA(B, 99)
    float* o = ws + PFSP_OFF + (size_t)b * CC * NN + n;
    #pragma unroll
    for (int c = 0; c < CC; ++c)
        *(float2*)(o + (size_t)c * NN) = acc[c];
}

// ---------------- K5: 3x3 conv, 16 -> 2 channels, + bias ---------------- (unchanged)
__global__ __launch_bounds__(256) void k_conv(const float* __restrict__ w_ds,
                                              const float* __restrict__ b_ds,
                                              const float* __restrict__ ws,
                                              float* __restrict__ out) {
    int b = blockIdx.y;
    int n = blockIdx.x * 256 + threadIdx.x;
    __shared__ float wl[2][CC][9];
    __shared__ float bl[2];
    for (int i = threadIdx.x; i < 2 * CC * 9; i += 256)
        ((float*)wl)[i] = w_ds[i];
    if (threadIdx.x < 2) bl[threadIdx.x] = b_ds[threadIdx.x];
    __syncthreads();
    int y = n >> 8, x = n & 255;
    const float* base = ws + PFSP_OFF + (size_t)b * CC * NN;
    float a0 = bl[0], a1 = bl[1];
    for (int c = 0; c < CC; ++c) {
        const float* pc = base + (size_t)c * NN;
        #pragma unroll
        for (int dy = -1; dy <= 1; ++dy) {
            int yy = y + dy;
            if (yy < 0 || yy >= HH) continue;
            #pragma unroll
            for (int dx = -1; dx <= 1; ++dx) {
                int xx = x + dx;
                if (xx < 0 || xx >= WW) continue;
                float v = pc[(size_t)yy * WW + xx];
                int k = (dy + 1) * 3 + (dx + 1);
                a0 += v * wl[0][c][k];
                a1 += v * wl[1][c][k];
            }
        }
    }
    out[((size_t)b * 2 + 0) * NN + n] = a0;
    out[((size_t)b * 2 + 1) * NN + n] = a1;
}

extern "C" void kernel_launch(void* const* d_in, const int* in_sizes, int n_in,
                              void* d_out, int out_size, void* d_ws, size_t ws_size,
                              hipStream_t stream) {
    const float* pf   = (const float*)d_in[0];
    const float* spf1 = (const float*)d_in[1];
    const float* spf2 = (const float*)d_in[2];
    const float* Q1   = (const float*)d_in[3];
    const float* Q2   = (const float*)d_in[4];
    const float* w_ds = (const float*)d_in[5];
    const float* b_ds = (const float*)d_in[6];
    float* ws  = (float*)d_ws;
    float* out = (float*)d_out;

    k_pass1<<<2560, 256, 0, stream>>>(pf, Q1, Q2, ws);
    k_reduceP<<<dim3(10, 8), 256, 0, stream>>>(ws);
    k_finalize<<<8, 256, 0, stream>>>(spf1, spf2, ws);
    k_pass2<<<dim3(NN / 256, BB), 128, 0, stream>>>(Q1, Q2, ws);
    k_conv<<<dim3(NN / 256, BB), 256, 0, stream>>>(w_ds, b_ds, ws, out);
}

// Round 13
// 162.235 us; speedup vs baseline: 1.1358x; 1.1358x over previous
//
#include <hip/hip_runtime.h>

// Problem constants
#define BB 4
#define CC 16
#define HH 256
#define WW 256
#define NN (HH*WW)      // 65536
#define SS 100
#define EPSV 1e-32f

// ws layout (float offsets)
#define PQ_OFF    0u                      // [8 bq][100 s][17]             = 13600
#define SPFN_OFF  13600u                  // [8 bq][100 s][16 c]           = 12800
#define PFSP_OFF  26400u                  // [4][16][65536]                = 4194304
#define PPART_OFF PFSP_OFF                // [8][128 hw][100 s][2 row][17] = 3481600
// PPART aliases PFSP: consumed by k_reduceP before k_pass2 overwrites.
// total = 26400 + 4194304 floats = 16.9 MB

__device__ __forceinline__ float dot4(const float4& a, const float4& b) {
    return a.x * b.x + a.y * b.y + a.z * b.z + a.w * b.w;
}
__device__ __forceinline__ float sum4(const float4& a) {
    return a.x + a.y + a.z + a.w;
}

// DPP lane-combine. Uniform control flow only (R9 lesson).
#define DPPQP(x, ctrl) __int_as_float(__builtin_amdgcn_update_dpp( \
    0, __float_as_int(x), ctrl, 0xF, 0xF, true))
// 0xB1 quad_perm xor1; 0x4E quad_perm xor2; 0x114 row_shr:4; 0x118 row_shr:8

// Pin a float4 in VGPRs: compiler may not rematerialize (reload) it.
#define PIN4(p) asm volatile("" : "+v"(p.x), "+v"(p.y), "+v"(p.z), "+v"(p.w));

// ---------------- pass1 (K1) ----------------
// R10 structure: wave owns (bq, 512-px half-window, 8-ch half, 20-s slice),
// pf in 16 float4 regs — now PINNED (R10/R11 VGPR=56 proved remat/reload).
// Per s: 2KB Q load, 16 dot4, reduce to ROW-PAIR level: pair(xor1)+sel,
// quad(xor2)+sel, row_shr4+8, one shfl_xor32. Lanes 12-15/28-31 store
// [2 row][17]; qsum via 4-DPP row chain + xor32.
#define QLD(X, k) \
    X##0 = *(const float4*)(qptr + (size_t)(k) * NN); \
    X##1 = *(const float4*)(qptr + (size_t)(k) * NN + 256);

#define P1_STEP(X, sidx) { \
    float t0 = dot4(p00,X##0)+dot4(p01,X##1); \
    float t1 = dot4(p10,X##0)+dot4(p11,X##1); \
    float t2 = dot4(p20,X##0)+dot4(p21,X##1); \
    float t3 = dot4(p30,X##0)+dot4(p31,X##1); \
    float t4 = dot4(p40,X##0)+dot4(p41,X##1); \
    float t5 = dot4(p50,X##0)+dot4(p51,X##1); \
    float t6 = dot4(p60,X##0)+dot4(p61,X##1); \
    float t7 = dot4(p70,X##0)+dot4(p71,X##1); \
    t0 += DPPQP(t0,0xB1); t1 += DPPQP(t1,0xB1); \
    t2 += DPPQP(t2,0xB1); t3 += DPPQP(t3,0xB1); \
    t4 += DPPQP(t4,0xB1); t5 += DPPQP(t5,0xB1); \
    t6 += DPPQP(t6,0xB1); t7 += DPPQP(t7,0xB1); \
    float u0 = odd ? t1 : t0; float u1 = odd ? t3 : t2; \
    float u2 = odd ? t5 : t4; float u3 = odd ? t7 : t6; \
    u0 += DPPQP(u0,0x4E); u1 += DPPQP(u1,0x4E); \
    u2 += DPPQP(u2,0x4E); u3 += DPPQP(u3,0x4E); \
    float w0 = hi2 ? u1 : u0; float w1 = hi2 ? u3 : u2; \
    w0 += DPPQP(w0,0x114); w1 += DPPQP(w1,0x114); \
    w0 += DPPQP(w0,0x118); w1 += DPPQP(w1,0x118); \
    w0 += __shfl_xor(w0,32); w1 += __shfl_xor(w1,32); \
    if (ch8 == 0) { \
        float qv = sum4(X##0)+sum4(X##1); \
        qv += DPPQP(qv,0xB1); qv += DPPQP(qv,0x4E); \
        qv += DPPQP(qv,0x114); qv += DPPQP(qv,0x118); \
        qv += __shfl_xor(qv,32); \
        if ((lane & 15) == 15 && lane < 32) \
            sout[(size_t)(sidx)*34 + (lane>>4)*17 + 16] = qv; \
    } \
    if ((lane & 15) >= 12 && lane < 32) { \
        float* o = sout + (size_t)(sidx)*34 + (lane>>4)*17 + ch8 + (lane & 3); \
        o[0] = w0; o[4] = w1; \
    } \
}

__global__ __launch_bounds__(256, 2) void k_pass1(const float* __restrict__ pf,
                                                  const float* __restrict__ Q1,
                                                  const float* __restrict__ Q2,
                                                  float* __restrict__ ws) {
    int tid = threadIdx.x, wid = tid >> 6, lane = tid & 63;
    int h  = wid & 1;          // channel half
    int nh = wid >> 1;         // n half
    int win = blockIdx.x;      // 0..63
    int sp  = blockIdx.y;      // 0..4
    int bq  = blockIdx.z;      // 0..7
    int b = bq >> 1, q = bq & 1;
    bool odd = lane & 1;
    bool hi2 = lane & 2;
    int ch8 = h * 8;

    int nbase = win * 1024 + nh * 512 + lane * 4;
    const float* qptr = (q ? Q2 : Q1) + (size_t)b * SS * NN
                        + (size_t)(sp * 20) * NN + nbase;
    const float* PF   = pf + (size_t)b * CC * NN + (size_t)ch8 * NN + nbase;

    // pf: 8 channels x 2 positions, persistent (PINNED) in registers
    float4 p00 = *(const float4*)(PF + (size_t)0 * NN);
    float4 p01 = *(const float4*)(PF + (size_t)0 * NN + 256);
    float4 p10 = *(const float4*)(PF + (size_t)1 * NN);
    float4 p11 = *(const float4*)(PF + (size_t)1 * NN + 256);
    float4 p20 = *(const float4*)(PF + (size_t)2 * NN);
    float4 p21 = *(const float4*)(PF + (size_t)2 * NN + 256);
    float4 p30 = *(const float4*)(PF + (size_t)3 * NN);
    float4 p31 = *(const float4*)(PF + (size_t)3 * NN + 256);
    float4 p40 = *(const float4*)(PF + (size_t)4 * NN);
    float4 p41 = *(const float4*)(PF + (size_t)4 * NN + 256);
    float4 p50 = *(const float4*)(PF + (size_t)5 * NN);
    float4 p51 = *(const float4*)(PF + (size_t)5 * NN + 256);
    float4 p60 = *(const float4*)(PF + (size_t)6 * NN);
    float4 p61 = *(const float4*)(PF + (size_t)6 * NN + 256);
    float4 p70 = *(const float4*)(PF + (size_t)7 * NN);
    float4 p71 = *(const float4*)(PF + (size_t)7 * NN + 256);
    PIN4(p00) PIN4(p01) PIN4(p10) PIN4(p11)
    PIN4(p20) PIN4(p21) PIN4(p30) PIN4(p31)
    PIN4(p40) PIN4(p41) PIN4(p50) PIN4(p51)
    PIN4(p60) PIN4(p61) PIN4(p70) PIN4(p71)

    float* sout = ws + PPART_OFF
                + (size_t)((bq * 64 + win) * 2 + nh) * 3400
                + (size_t)(sp * 20) * 34;

    float4 A0, A1, B0, B1;
    QLD(A, 0)
    for (int s = 0; s < 18; s += 2) {
        QLD(B, s + 1)
        P1_STEP(A, s)
        QLD(A, s + 2)
        P1_STEP(B, s + 1)
    }
    QLD(B, 19)
    P1_STEP(A, 18)
    P1_STEP(B, 19)
}

// ---------------- K2: reduce window partials ----------------
// PQ[bq][s][17] = sum over 128 hw x 2 rows of PPART.
__global__ __launch_bounds__(256) void k_reduceP(float* __restrict__ ws) {
    int sgc = blockIdx.x;  // 0..9 (10 s each)
    int bq  = blockIdx.y;  // 0..7
    int tid = threadIdx.x;
    if (tid < 170) {
        int sl = tid / 17, c = tid % 17;
        const float* p = ws + PPART_OFF + (size_t)(bq * 128) * 3400
                       + (size_t)(sgc * 10 + sl) * 34 + c;
        float a0 = 0.f, a1 = 0.f, a2 = 0.f, a3 = 0.f;
        #pragma unroll 4
        for (int hw = 0; hw < 128; hw += 2) {
            a0 += p[(size_t)hw * 3400];
            a1 += p[(size_t)hw * 3400 + 17];
            a2 += p[(size_t)(hw + 1) * 3400];
            a3 += p[(size_t)(hw + 1) * 3400 + 17];
        }
        ws[PQ_OFF + (size_t)(bq * 100 + sgc * 10 + sl) * 17 + c]
            = (a0 + a1) + (a2 + a3);
    }
}

// ---------------- K3: rels + finalize (s-quarter split) ----------------
// spf_n[s][c] = (sum_t rels[s,t]P[c,t]) / (sum_t rels[s,t]qsum[t]+eps)
__global__ __launch_bounds__(256) void k_finalize(const float* __restrict__ spf1,
                                                  const float* __restrict__ spf2,
                                                  float* __restrict__ ws) {
    int sq = blockIdx.x;  // 0..3 (25 s each)
    int bq = blockIdx.y;  // 0..7
    int b = bq >> 1, q = bq & 1;
    __shared__ float sp[CC][SS];        // 6.4 KB
    __shared__ float rl[25][SS + 1];    // 10.1 KB
    __shared__ float Pl[CC * SS];       // 6.4 KB
    __shared__ float qs[SS];
    __shared__ float den[25];
    int tid = threadIdx.x;

    const float* spf = (q ? spf2 : spf1) + (size_t)b * CC * SS;
    for (int i = tid; i < CC * SS; i += 256) sp[i / SS][i % SS] = spf[i];
    const float* pq = ws + PQ_OFF + (size_t)bq * 100 * 17;
    for (int idx = tid; idx < CC * SS; idx += 256) {
        int c = idx / SS, t = idx % SS;
        Pl[idx] = pq[(size_t)t * 17 + c];
    }
    if (tid < SS) qs[tid] = pq[(size_t)tid * 17 + 16];
    __syncthreads();
    for (int i = tid; i < 25 * SS; i += 256) {
        int sl = i / SS, t = i % SS;
        int s = sq * 25 + sl;
        float d2 = 0.f;
        #pragma unroll
        for (int c = 0; c < CC; ++c) {
            float d = sp[c][t] - sp[c][s];
            d2 += d * d;
        }
        rl[sl][t] = expf(-d2);
    }
    __syncthreads();
    if (tid < 25) {
        float a = 0.f;
        for (int t = 0; t < SS; ++t) a += rl[tid][t] * qs[t];
        den[tid] = a + EPSV;
    }
    __syncthreads();
    float* sout = ws + SPFN_OFF + (size_t)bq * SS * CC;
    for (int idx = tid; idx < 25 * CC; idx += 256) {
        int sl = idx / CC, c = idx % CC;
        float a = 0.f;
        for (int t = 0; t < SS; ++t) a += rl[sl][t] * Pl[c * SS + t];
        sout[(size_t)(sq * 25 + sl) * CC + c] = a / den[sl];
    }
}

// ---------------- K4: pf_sp = spf1n@Q1 + spf2n@Q2 ----------------
// No LDS: spf values are wave-uniform, read from global with uniform
// addresses -> s_load (SMEM pipe). Thread owns 2 px (float2), A/B prefetch.
// (No token pasting in this macro: V1/V2 are the actual prefetch registers.)
#define P2STEP(V1, V2, s) { \
    _Pragma("unroll") for (int g = 0; g < 4; ++g) { \
        float4 s1 = *(const float4*)(sp1 + (s) * CC + g * 4); \
        float4 s2 = *(const float4*)(sp2 + (s) * CC + g * 4); \
        acc[g*4+0].x += s1.x*V1.x + s2.x*V2.x; \
        acc[g*4+0].y += s1.x*V1.y + s2.x*V2.y; \
        acc[g*4+1].x += s1.y*V1.x + s2.y*V2.x; \
        acc[g*4+1].y += s1.y*V1.y + s2.y*V2.y; \
        acc[g*4+2].x += s1.z*V1.x + s2.z*V2.x; \
        acc[g*4+2].y += s1.z*V1.y + s2.z*V2.y; \
        acc[g*4+3].x += s1.w*V1.x + s2.w*V2.x; \
        acc[g*4+3].y += s1.w*V1.y + s2.w*V2.y; } }

__global__ __launch_bounds__(256) void k_pass2(const float* __restrict__ Q1,
                                               const float* __restrict__ Q2,
                                               float* __restrict__ ws) {
    int blk = blockIdx.x;   // 0..127
    int b   = blockIdx.y;
    int tid = threadIdx.x;
    int n = blk * 512 + tid * 2;
    const float* q1p = Q1 + (size_t)b * SS * NN + n;
    const float* q2p = Q2 + (size_t)b * SS * NN + n;
    const float* sp1 = ws + SPFN_OFF + (size_t)(b * 2 + 0) * SS * CC;
    const float* sp2 = ws + SPFN_OFF + (size_t)(b * 2 + 1) * SS * CC;
    float2 acc[CC];
    #pragma unroll
    for (int c = 0; c < CC; ++c) acc[c] = make_float2(0.f, 0.f);
    float2 A1, A2, B1, B2;
    A1 = *(const float2*)(q1p);
    A2 = *(const float2*)(q2p);
    #pragma unroll 2
    for (int s = 0; s < 98; s += 2) {
        B1 = *(const float2*)(q1p + (size_t)(s + 1) * NN);
        B2 = *(const float2*)(q2p + (size_t)(s + 1) * NN);
        P2STEP(A1, A2, s)
        A1 = *(const float2*)(q1p + (size_t)(s + 2) * NN);
        A2 = *(const float2*)(q2p + (size_t)(s + 2) * NN);
        P2STEP(B1, B2, s + 1)
    }
    B1 = *(const float2*)(q1p + (size_t)99 * NN);
    B2 = *(const float2*)(q2p + (size_t)99 * NN);
    P2STEP(A1, A2, 98)
    P2STEP(B1, B2, 99)
    float* o = ws + PFSP_OFF + (size_t)b * CC * NN + n;
    #pragma unroll
    for (int c = 0; c < CC; ++c)
        *(float2*)(o + (size_t)c * NN) = acc[c];
}

// ---------------- K5: 3x3 conv, 16 -> 2 channels, + bias ----------------
__global__ __launch_bounds__(256) void k_conv(const float* __restrict__ w_ds,
                                              const float* __restrict__ b_ds,
                                              const float* __restrict__ ws,
                                              float* __restrict__ out) {
    int b = blockIdx.y;
    int n = blockIdx.x * 256 + threadIdx.x;
    __shared__ float wl[2][CC][9];
    __shared__ float bl[2];
    for (int i = threadIdx.x; i < 2 * CC * 9; i += 256)
        ((float*)wl)[i] = w_ds[i];
    if (threadIdx.x < 2) bl[threadIdx.x] = b_ds[threadIdx.x];
    __syncthreads();
    int y = n >> 8, x = n & 255;
    const float* base = ws + PFSP_OFF + (size_t)b * CC * NN;
    float a0 = bl[0], a1 = bl[1];
    for (int c = 0; c < CC; ++c) {
        const float* pc = base + (size_t)c * NN;
        #pragma unroll
        for (int dy = -1; dy <= 1; ++dy) {
            int yy = y + dy;
            if (yy < 0 || yy >= HH) continue;
            #pragma unroll
            for (int dx = -1; dx <= 1; ++dx) {
                int xx = x + dx;
                if (xx < 0 || xx >= WW) continue;
                float v = pc[(size_t)yy * WW + xx];
                int k = (dy + 1) * 3 + (dx + 1);
                a0 += v * wl[0][c][k];
                a1 += v * wl[1][c][k];
            }
        }
    }
    out[((size_t)b * 2 + 0) * NN + n] = a0;
    out[((size_t)b * 2 + 1) * NN + n] = a1;
}

extern "C" void kernel_launch(void* const* d_in, const int* in_sizes, int n_in,
                              void* d_out, int out_size, void* d_ws, size_t ws_size,
                              hipStream_t stream) {
    const float* pf   = (const float*)d_in[0];
    const float* spf1 = (const float*)d_in[1];
    const float* spf2 = (const float*)d_in[2];
    const float* Q1   = (const float*)d_in[3];
    const float* Q2   = (const float*)d_in[4];
    const float* w_ds = (const float*)d_in[5];
    const float* b_ds = (const float*)d_in[6];
    float* ws  = (float*)d_ws;
    float* out = (float*)d_out;

    k_pass1<<<dim3(64, 5, 8), 256, 0, stream>>>(pf, Q1, Q2, ws);
    k_reduceP<<<dim3(10, 8), 256, 0, stream>>>(ws);
    k_finalize<<<dim3(4, 8), 256, 0, stream>>>(spf1, spf2, ws);
    k_pass2<<<dim3(128, BB), 256, 0, stream>>>(Q1, Q2, ws);
    k_conv<<<dim3(NN / 256, BB), 256, 0, stream>>>(w_ds, b_ds, ws, out);
}

// Round 14
// 160.906 us; speedup vs baseline: 1.1452x; 1.0083x over previous
//
#include <hip/hip_runtime.h>

// Problem constants
#define BB 4
#define CC 16
#define HH 256
#define WW 256
#define NN (HH*WW)      // 65536
#define SS 100
#define EPSV 1e-32f

// ws layout (float offsets)
#define PQ_OFF    0u                      // [8 bq][100 s][17]             = 13600
#define SPFN_OFF  13600u                  // [8 bq][100 s][16 c]           = 12800
#define PFSP_OFF  26400u                  // [4][16][65536]                = 4194304
#define PPART_OFF PFSP_OFF                // [8][128 hw][100 s][2 row][17] = 3481600
// PPART aliases PFSP: consumed by k_reduceP before k_pass2 overwrites.
// total = 26400 + 4194304 floats = 16.9 MB

__device__ __forceinline__ float dot4(const float4& a, const float4& b) {
    return a.x * b.x + a.y * b.y + a.z * b.z + a.w * b.w;
}
__device__ __forceinline__ float sum4(const float4& a) {
    return a.x + a.y + a.z + a.w;
}

// DPP lane-combine. Uniform control flow only (R9 lesson).
#define DPPQP(x, ctrl) __int_as_float(__builtin_amdgcn_update_dpp( \
    0, __float_as_int(x), ctrl, 0xF, 0xF, true))
// 0xB1 quad_perm xor1; 0x4E quad_perm xor2; 0x114 row_shr:4; 0x118 row_shr:8

// Re-pin a float4 in VGPRs. Applied EVERY step: each step's uses reference
// the previous asm's outputs, which regalloc cannot rematerialize -> pf
// stays truly register-resident (R13: one-shot pin failed, VGPR stayed 56).
#define PIN4(p) asm volatile("" : "+v"(p.x), "+v"(p.y), "+v"(p.z), "+v"(p.w));
#define PIN_PF  PIN4(p00) PIN4(p01) PIN4(p10) PIN4(p11) \
                PIN4(p20) PIN4(p21) PIN4(p30) PIN4(p31) \
                PIN4(p40) PIN4(p41) PIN4(p50) PIN4(p51) \
                PIN4(p60) PIN4(p61) PIN4(p70) PIN4(p71)

// ---------------- pass1 (K1) ----------------
// Wave owns (bq, 512-px half-window, 8-ch half, 20-s slice). pf in 16
// PINNED float4 regs. Fully-unrolled straight-line s-loop (no backedge ->
// pf loads CSE to one; compiler software-pipelines the Q loads). Per s:
// 2KB Q load, 16 dot4, reduce to ROW-PAIR level (pair xor1 + sel, quad
// xor2 + sel, row_shr4+8, one shfl_xor32). Lanes 12-15/28-31 store
// [2 row][17]; qsum via 4-DPP row chain + xor32 on h==0 waves.
#define P1_STEP(Q0, Q1v, sidx) { \
    float t0 = dot4(p00,Q0)+dot4(p01,Q1v); \
    float t1 = dot4(p10,Q0)+dot4(p11,Q1v); \
    float t2 = dot4(p20,Q0)+dot4(p21,Q1v); \
    float t3 = dot4(p30,Q0)+dot4(p31,Q1v); \
    float t4 = dot4(p40,Q0)+dot4(p41,Q1v); \
    float t5 = dot4(p50,Q0)+dot4(p51,Q1v); \
    float t6 = dot4(p60,Q0)+dot4(p61,Q1v); \
    float t7 = dot4(p70,Q0)+dot4(p71,Q1v); \
    t0 += DPPQP(t0,0xB1); t1 += DPPQP(t1,0xB1); \
    t2 += DPPQP(t2,0xB1); t3 += DPPQP(t3,0xB1); \
    t4 += DPPQP(t4,0xB1); t5 += DPPQP(t5,0xB1); \
    t6 += DPPQP(t6,0xB1); t7 += DPPQP(t7,0xB1); \
    float u0 = odd ? t1 : t0; float u1 = odd ? t3 : t2; \
    float u2 = odd ? t5 : t4; float u3 = odd ? t7 : t6; \
    u0 += DPPQP(u0,0x4E); u1 += DPPQP(u1,0x4E); \
    u2 += DPPQP(u2,0x4E); u3 += DPPQP(u3,0x4E); \
    float w0 = hi2 ? u1 : u0; float w1 = hi2 ? u3 : u2; \
    w0 += DPPQP(w0,0x114); w1 += DPPQP(w1,0x114); \
    w0 += DPPQP(w0,0x118); w1 += DPPQP(w1,0x118); \
    w0 += __shfl_xor(w0,32); w1 += __shfl_xor(w1,32); \
    if (ch8 == 0) { \
        float qv = sum4(Q0)+sum4(Q1v); \
        qv += DPPQP(qv,0xB1); qv += DPPQP(qv,0x4E); \
        qv += DPPQP(qv,0x114); qv += DPPQP(qv,0x118); \
        qv += __shfl_xor(qv,32); \
        if ((lane & 15) == 15 && lane < 32) \
            sout[(size_t)(sidx)*34 + (lane>>4)*17 + 16] = qv; \
    } \
    if ((lane & 15) >= 12 && lane < 32) { \
        float* o = sout + (size_t)(sidx)*34 + (lane>>4)*17 + ch8 + (lane & 3); \
        o[0] = w0; o[4] = w1; \
    } \
}

__global__ __launch_bounds__(256, 2) void k_pass1(const float* __restrict__ pf,
                                                  const float* __restrict__ Q1,
                                                  const float* __restrict__ Q2,
                                                  float* __restrict__ ws) {
    int tid = threadIdx.x, wid = tid >> 6, lane = tid & 63;
    int h  = wid & 1;          // channel half
    int nh = wid >> 1;         // n half
    int win = blockIdx.x;      // 0..63
    int sp  = blockIdx.y;      // 0..4
    int bq  = blockIdx.z;      // 0..7
    int b = bq >> 1, q = bq & 1;
    bool odd = lane & 1;
    bool hi2 = lane & 2;
    int ch8 = h * 8;

    int nbase = win * 1024 + nh * 512 + lane * 4;
    const float* qptr = (q ? Q2 : Q1) + (size_t)b * SS * NN
                        + (size_t)(sp * 20) * NN + nbase;
    const float* PF   = pf + (size_t)b * CC * NN + (size_t)ch8 * NN + nbase;

    // pf: 8 channels x 2 positions, persistent in registers
    float4 p00 = *(const float4*)(PF + (size_t)0 * NN);
    float4 p01 = *(const float4*)(PF + (size_t)0 * NN + 256);
    float4 p10 = *(const float4*)(PF + (size_t)1 * NN);
    float4 p11 = *(const float4*)(PF + (size_t)1 * NN + 256);
    float4 p20 = *(const float4*)(PF + (size_t)2 * NN);
    float4 p21 = *(const float4*)(PF + (size_t)2 * NN + 256);
    float4 p30 = *(const float4*)(PF + (size_t)3 * NN);
    float4 p31 = *(const float4*)(PF + (size_t)3 * NN + 256);
    float4 p40 = *(const float4*)(PF + (size_t)4 * NN);
    float4 p41 = *(const float4*)(PF + (size_t)4 * NN + 256);
    float4 p50 = *(const float4*)(PF + (size_t)5 * NN);
    float4 p51 = *(const float4*)(PF + (size_t)5 * NN + 256);
    float4 p60 = *(const float4*)(PF + (size_t)6 * NN);
    float4 p61 = *(const float4*)(PF + (size_t)6 * NN + 256);
    float4 p70 = *(const float4*)(PF + (size_t)7 * NN);
    float4 p71 = *(const float4*)(PF + (size_t)7 * NN + 256);

    float* sout = ws + PPART_OFF
                + (size_t)((bq * 64 + win) * 2 + nh) * 3400
                + (size_t)(sp * 20) * 34;

    #pragma unroll
    for (int s = 0; s < 20; ++s) {
        PIN_PF
        float4 Qa = *(const float4*)(qptr + (size_t)s * NN);
        float4 Qb = *(const float4*)(qptr + (size_t)s * NN + 256);
        P1_STEP(Qa, Qb, s)
    }
}

// ---------------- K2: reduce window partials ----------------
// PQ[bq][s][17] = sum over 128 hw x 2 rows of PPART.
__global__ __launch_bounds__(256) void k_reduceP(float* __restrict__ ws) {
    int sgc = blockIdx.x;  // 0..9 (10 s each)
    int bq  = blockIdx.y;  // 0..7
    int tid = threadIdx.x;
    if (tid < 170) {
        int sl = tid / 17, c = tid % 17;
        const float* p = ws + PPART_OFF + (size_t)(bq * 128) * 3400
                       + (size_t)(sgc * 10 + sl) * 34 + c;
        float a0 = 0.f, a1 = 0.f, a2 = 0.f, a3 = 0.f;
        #pragma unroll 4
        for (int hw = 0; hw < 128; hw += 2) {
            a0 += p[(size_t)hw * 3400];
            a1 += p[(size_t)hw * 3400 + 17];
            a2 += p[(size_t)(hw + 1) * 3400];
            a3 += p[(size_t)(hw + 1) * 3400 + 17];
        }
        ws[PQ_OFF + (size_t)(bq * 100 + sgc * 10 + sl) * 17 + c]
            = (a0 + a1) + (a2 + a3);
    }
}

// ---------------- K3: rels + finalize (s-quarter split) ----------------
__global__ __launch_bounds__(256) void k_finalize(const float* __restrict__ spf1,
                                                  const float* __restrict__ spf2,
                                                  float* __restrict__ ws) {
    int sq = blockIdx.x;  // 0..3 (25 s each)
    int bq = blockIdx.y;  // 0..7
    int b = bq >> 1, q = bq & 1;
    __shared__ float sp[CC][SS];
    __shared__ float rl[25][SS + 1];
    __shared__ float Pl[CC * SS];
    __shared__ float qs[SS];
    __shared__ float den[25];
    int tid = threadIdx.x;

    const float* spf = (q ? spf2 : spf1) + (size_t)b * CC * SS;
    for (int i = tid; i < CC * SS; i += 256) sp[i / SS][i % SS] = spf[i];
    const float* pq = ws + PQ_OFF + (size_t)bq * 100 * 17;
    for (int idx = tid; idx < CC * SS; idx += 256) {
        int c = idx / SS, t = idx % SS;
        Pl[idx] = pq[(size_t)t * 17 + c];
    }
    if (tid < SS) qs[tid] = pq[(size_t)tid * 17 + 16];
    __syncthreads();
    for (int i = tid; i < 25 * SS; i += 256) {
        int sl = i / SS, t = i % SS;
        int s = sq * 25 + sl;
        float d2 = 0.f;
        #pragma unroll
        for (int c = 0; c < CC; ++c) {
            float d = sp[c][t] - sp[c][s];
            d2 += d * d;
        }
        rl[sl][t] = expf(-d2);
    }
    __syncthreads();
    if (tid < 25) {
        float a = 0.f;
        for (int t = 0; t < SS; ++t) a += rl[tid][t] * qs[t];
        den[tid] = a + EPSV;
    }
    __syncthreads();
    float* sout = ws + SPFN_OFF + (size_t)bq * SS * CC;
    for (int idx = tid; idx < 25 * CC; idx += 256) {
        int sl = idx / CC, c = idx % CC;
        float a = 0.f;
        for (int t = 0; t < SS; ++t) a += rl[sl][t] * Pl[c * SS + t];
        sout[(size_t)(sq * 25 + sl) * CC + c] = a / den[sl];
    }
}

// ---------------- K4: pf_sp = spf1n@Q1 + spf2n@Q2 ----------------
// spf values are wave-uniform -> uniform global reads lower to s_load
// (SMEM pipe). Thread owns 2 px (float2), A/B prefetch. No token pasting.
#define P2STEP(V1, V2, s) { \
    _Pragma("unroll") for (int g = 0; g < 4; ++g) { \
        float4 s1 = *(const float4*)(sp1 + (s) * CC + g * 4); \
        float4 s2 = *(const float4*)(sp2 + (s) * CC + g * 4); \
        acc[g*4+0].x += s1.x*V1.x + s2.x*V2.x; \
        acc[g*4+0].y += s1.x*V1.y + s2.x*V2.y; \
        acc[g*4+1].x += s1.y*V1.x + s2.y*V2.x; \
        acc[g*4+1].y += s1.y*V1.y + s2.y*V2.y; \
        acc[g*4+2].x += s1.z*V1.x + s2.z*V2.x; \
        acc[g*4+2].y += s1.z*V1.y + s2.z*V2.y; \
        acc[g*4+3].x += s1.w*V1.x + s2.w*V2.x; \
        acc[g*4+3].y += s1.w*V1.y + s2.w*V2.y; } }

__global__ __launch_bounds__(256) void k_pass2(const float* __restrict__ Q1,
                                               const float* __restrict__ Q2,
                                               float* __restrict__ ws) {
    int blk = blockIdx.x;   // 0..127
    int b   = blockIdx.y;
    int tid = threadIdx.x;
    int n = blk * 512 + tid * 2;
    const float* q1p = Q1 + (size_t)b * SS * NN + n;
    const float* q2p = Q2 + (size_t)b * SS * NN + n;
    const float* sp1 = ws + SPFN_OFF + (size_t)(b * 2 + 0) * SS * CC;
    const float* sp2 = ws + SPFN_OFF + (size_t)(b * 2 + 1) * SS * CC;
    float2 acc[CC];
    #pragma unroll
    for (int c = 0; c < CC; ++c) acc[c] = make_float2(0.f, 0.f);
    float2 A1, A2, B1, B2;
    A1 = *(const float2*)(q1p);
    A2 = *(const float2*)(q2p);
    #pragma unroll 2
    for (int s = 0; s < 98; s += 2) {
        B1 = *(const float2*)(q1p + (size_t)(s + 1) * NN);
        B2 = *(const float2*)(q2p + (size_t)(s + 1) * NN);
        P2STEP(A1, A2, s)
        A1 = *(const float2*)(q1p + (size_t)(s + 2) * NN);
        A2 = *(const float2*)(q2p + (size_t)(s + 2) * NN);
        P2STEP(B1, B2, s + 1)
    }
    B1 = *(const float2*)(q1p + (size_t)99 * NN);
    B2 = *(const float2*)(q2p + (size_t)99 * NN);
    P2STEP(A1, A2, 98)
    P2STEP(B1, B2, 99)
    float* o = ws + PFSP_OFF + (size_t)b * CC * NN + n;
    #pragma unroll
    for (int c = 0; c < CC; ++c)
        *(float2*)(o + (size_t)c * NN) = acc[c];
}

// ---------------- K5: 3x3 conv, 16 -> 2 channels, + bias ----------------
__global__ __launch_bounds__(256) void k_conv(const float* __restrict__ w_ds,
                                              const float* __restrict__ b_ds,
                                              const float* __restrict__ ws,
                                              float* __restrict__ out) {
    int b = blockIdx.y;
    int n = blockIdx.x * 256 + threadIdx.x;
    __shared__ float wl[2][CC][9];
    __shared__ float bl[2];
    for (int i = threadIdx.x; i < 2 * CC * 9; i += 256)
        ((float*)wl)[i] = w_ds[i];
    if (threadIdx.x < 2) bl[threadIdx.x] = b_ds[threadIdx.x];
    __syncthreads();
    int y = n >> 8, x = n & 255;
    const float* base = ws + PFSP_OFF + (size_t)b * CC * NN;
    float a0 = bl[0], a1 = bl[1];
    for (int c = 0; c < CC; ++c) {
        const float* pc = base + (size_t)c * NN;
        #pragma unroll
        for (int dy = -1; dy <= 1; ++dy) {
            int yy = y + dy;
            if (yy < 0 || yy >= HH) continue;
            #pragma unroll
            for (int dx = -1; dx <= 1; ++dx) {
                int xx = x + dx;
                if (xx < 0 || xx >= WW) continue;
                float v = pc[(size_t)yy * WW + xx];
                int k = (dy + 1) * 3 + (dx + 1);
                a0 += v * wl[0][c][k];
                a1 += v * wl[1][c][k];
            }
        }
    }
    out[((size_t)b * 2 + 0) * NN + n] = a0;
    out[((size_t)b * 2 + 1) * NN + n] = a1;
}

extern "C" void kernel_launch(void* const* d_in, const int* in_sizes, int n_in,
                              void* d_out, int out_size, void* d_ws, size_t ws_size,
                              hipStream_t stream) {
    const float* pf   = (const float*)d_in[0];
    const float* spf1 = (const float*)d_in[1];
    const float* spf2 = (const float*)d_in[2];
    const float* Q1   = (const float*)d_in[3];
    const float* Q2   = (const float*)d_in[4];
    const float* w_ds = (const float*)d_in[5];
    const float* b_ds = (const float*)d_in[6];
    float* ws  = (float*)d_ws;
    float* out = (float*)d_out;

    k_pass1<<<dim3(64, 5, 8), 256, 0, stream>>>(pf, Q1, Q2, ws);
    k_reduceP<<<dim3(10, 8), 256, 0, stream>>>(ws);
    k_finalize<<<dim3(4, 8), 256, 0, stream>>>(spf1, spf2, ws);
    k_pass2<<<dim3(128, BB), 256, 0, stream>>>(Q1, Q2, ws);
    k_conv<<<dim3(NN / 256, BB), 256, 0, stream>>>(w_ds, b_ds, ws, out);
}

// Round 15
// 159.449 us; speedup vs baseline: 1.1556x; 1.0091x over previous
//
#include <hip/hip_runtime.h>

// Problem constants
#define BB 4
#define CC 16
#define HH 256
#define WW 256
#define NN (HH*WW)      // 65536
#define SS 100
#define EPSV 1e-32f

// ws layout (float offsets)
#define PQ_OFF    0u                      // [8 bq][100 s][2 row][17]      = 27200
#define SPFN_OFF  27200u                  // [8 bq][100 s][16 c]           = 12800
#define PFSP_OFF  40000u                  // [4][16][65536]                = 4194304
#define PPART_OFF PFSP_OFF                // [8][128 win][100 s][2 row][17]= 3481600
// PPART aliases PFSP: consumed by k_reduceP before k_pass2 overwrites.
// total = 40000 + 4194304 floats = 16.9 MB

__device__ __forceinline__ float dot4(const float4& a, const float4& b) {
    return a.x * b.x + a.y * b.y + a.z * b.z + a.w * b.w;
}
__device__ __forceinline__ float sum4(const float4& a) {
    return a.x + a.y + a.z + a.w;
}

// DPP lane-combine. Uniform control flow only (R9 lesson).
#define DPPQP(x, ctrl) __int_as_float(__builtin_amdgcn_update_dpp( \
    0, __float_as_int(x), ctrl, 0xF, 0xF, true))
// 0xB1 qp xor1; 0x4E qp xor2; 0x111/0x112/0x114/0x118 row_shr 1/2/4/8

// Un-rematerializable load: asm results cannot be re-derived by regalloc,
// so pf stays truly register-resident (R10-R14: VGPR 48-60 proved the
// compiler reloads plain-HIP pf loads every step -> 18 VMEM/step -> L1-bound).
#define ASM_LD4(dst, addr) \
    asm volatile("global_load_dwordx4 %0, %1, off" : "=v"(dst) : "v"(addr));

// ---------------- pass1 (K1) ----------------
// Block = 512-px window, 4 waves x 4 channels (all waves same Q bytes -> L1
// hits). pf = 8 float4/lane via asm loads. Per s: 2 Q float4 loads (lane's
// 8 px), 8 dot4, row-pair reduce (pair xor1 + sel, quad xor2 + sel ->
// c=lane&3, row_shr4+8, one shfl_xor16). Lanes {12-15,44-47} store 4 c each;
// wave 0 also reduces qsum (row_shr chain, lanes 15/47 store).
#define P1_STEP(QA, QB, sidx) { \
    float t0 = dot4(p00,QA)+dot4(p01,QB); \
    float t1 = dot4(p10,QA)+dot4(p11,QB); \
    float t2 = dot4(p20,QA)+dot4(p21,QB); \
    float t3 = dot4(p30,QA)+dot4(p31,QB); \
    t0 += DPPQP(t0,0xB1); t1 += DPPQP(t1,0xB1); \
    t2 += DPPQP(t2,0xB1); t3 += DPPQP(t3,0xB1); \
    float u0 = odd ? t1 : t0; float u1 = odd ? t3 : t2; \
    u0 += DPPQP(u0,0x4E); u1 += DPPQP(u1,0x4E); \
    float w = hi2 ? u1 : u0; \
    w += DPPQP(w,0x114); \
    w += DPPQP(w,0x118); \
    w += __shfl_xor(w,16); \
    if (wid == 0) { \
        float qv = sum4(QA)+sum4(QB); \
        qv += DPPQP(qv,0x111); qv += DPPQP(qv,0x112); \
        qv += DPPQP(qv,0x114); qv += DPPQP(qv,0x118); \
        qv += __shfl_xor(qv,16); \
        if ((lane & 31) == 15) \
            sout[(size_t)(sidx)*34 + (lane>>5)*17 + 16] = qv; \
    } \
    if ((lane & 15) >= 12 && (lane & 16) == 0) \
        sout[(size_t)(sidx)*34 + (lane>>5)*17 + ch4 + (lane & 3)] = w; \
}

__global__ __launch_bounds__(256, 2) void k_pass1(const float* __restrict__ pf,
                                                  const float* __restrict__ Q1,
                                                  const float* __restrict__ Q2,
                                                  float* __restrict__ ws) {
    int tid = threadIdx.x, wid = tid >> 6, lane = tid & 63;
    int win = blockIdx.x;      // 0..127 (512-px window)
    int sp  = blockIdx.y;      // 0..4   (20-s slice)
    int bq  = blockIdx.z;      // 0..7
    int b = bq >> 1, q = bq & 1;
    bool odd = lane & 1;
    bool hi2 = lane & 2;
    int ch4 = wid * 4;

    int nbase = win * 512 + lane * 8;   // lane owns 8 px
    const float* qptr = (q ? Q2 : Q1) + (size_t)b * SS * NN
                        + (size_t)(sp * 20) * NN + nbase;
    const float* PF   = pf + (size_t)b * CC * NN + (size_t)ch4 * NN + nbase;

    // pf: 4 channels x 2 float4, register-pinned via asm loads
    float4 p00, p01, p10, p11, p20, p21, p30, p31;
    ASM_LD4(p00, PF)
    ASM_LD4(p01, PF + 4)
    ASM_LD4(p10, PF + (size_t)1 * NN)
    ASM_LD4(p11, PF + (size_t)1 * NN + 4)
    ASM_LD4(p20, PF + (size_t)2 * NN)
    ASM_LD4(p21, PF + (size_t)2 * NN + 4)
    ASM_LD4(p30, PF + (size_t)3 * NN)
    ASM_LD4(p31, PF + (size_t)3 * NN + 4)
    asm volatile("s_waitcnt vmcnt(0)" ::: "memory");

    float* sout = ws + PPART_OFF
                + ((size_t)(bq * 128 + win) * 100 + sp * 20) * 34;

    float4 Aa, Ab, Ba, Bb;
    Aa = *(const float4*)(qptr);
    Ab = *(const float4*)(qptr + 4);
    #pragma unroll
    for (int s = 0; s < 18; s += 2) {
        Ba = *(const float4*)(qptr + (size_t)(s + 1) * NN);
        Bb = *(const float4*)(qptr + (size_t)(s + 1) * NN + 4);
        P1_STEP(Aa, Ab, s)
        Aa = *(const float4*)(qptr + (size_t)(s + 2) * NN);
        Ab = *(const float4*)(qptr + (size_t)(s + 2) * NN + 4);
        P1_STEP(Ba, Bb, s + 1)
    }
    Ba = *(const float4*)(qptr + (size_t)19 * NN);
    Bb = *(const float4*)(qptr + (size_t)19 * NN + 4);
    P1_STEP(Aa, Ab, 18)
    P1_STEP(Ba, Bb, 19)
}

// ---------------- K2: reduce over 128 windows (coalesced) ----------------
// PQ[bq][3400] = sum_win PPART[bq][win][3400]. Strip-parallel.
__global__ __launch_bounds__(256) void k_reduceP(float* __restrict__ ws) {
    int strip = blockIdx.x;  // 0..13
    int bq    = blockIdx.y;  // 0..7
    int idx = strip * 256 + threadIdx.x;
    if (idx < 3400) {
        const float* pp = ws + PPART_OFF + (size_t)bq * 128 * 3400 + idx;
        float a0 = 0.f, a1 = 0.f;
        #pragma unroll 4
        for (int win = 0; win < 128; win += 2) {
            a0 += pp[(size_t)win * 3400];
            a1 += pp[(size_t)(win + 1) * 3400];
        }
        ws[PQ_OFF + (size_t)bq * 3400 + idx] = a0 + a1;
    }
}

// ---------------- K3: rels + finalize (s-quarter split) ----------------
// PQ layout [s][2 row][17]; rows folded here.
__global__ __launch_bounds__(256) void k_finalize(const float* __restrict__ spf1,
                                                  const float* __restrict__ spf2,
                                                  float* __restrict__ ws) {
    int sq = blockIdx.x;  // 0..3 (25 s each)
    int bq = blockIdx.y;  // 0..7
    int b = bq >> 1, q = bq & 1;
    __shared__ float sp[CC][SS];
    __shared__ float rl[25][SS + 1];
    __shared__ float Pl[CC * SS];
    __shared__ float qs[SS];
    __shared__ float den[25];
    int tid = threadIdx.x;

    const float* spf = (q ? spf2 : spf1) + (size_t)b * CC * SS;
    for (int i = tid; i < CC * SS; i += 256) sp[i / SS][i % SS] = spf[i];
    const float* pq = ws + PQ_OFF + (size_t)bq * 3400;
    for (int idx = tid; idx < CC * SS; idx += 256) {
        int c = idx / SS, t = idx % SS;
        Pl[idx] = pq[(size_t)t * 34 + c] + pq[(size_t)t * 34 + 17 + c];
    }
    if (tid < SS) qs[tid] = pq[(size_t)tid * 34 + 16] + pq[(size_t)tid * 34 + 33];
    __syncthreads();
    for (int i = tid; i < 25 * SS; i += 256) {
        int sl = i / SS, t = i % SS;
        int s = sq * 25 + sl;
        float d2 = 0.f;
        #pragma unroll
        for (int c = 0; c < CC; ++c) {
            float d = sp[c][t] - sp[c][s];
            d2 += d * d;
        }
        rl[sl][t] = expf(-d2);
    }
    __syncthreads();
    if (tid < 25) {
        float a = 0.f;
        for (int t = 0; t < SS; ++t) a += rl[tid][t] * qs[t];
        den[tid] = a + EPSV;
    }
    __syncthreads();
    float* sout = ws + SPFN_OFF + (size_t)bq * SS * CC;
    for (int idx = tid; idx < 25 * CC; idx += 256) {
        int sl = idx / CC, c = idx % CC;
        float a = 0.f;
        for (int t = 0; t < SS; ++t) a += rl[sl][t] * Pl[c * SS + t];
        sout[(size_t)(sq * 25 + sl) * CC + c] = a / den[sl];
    }
}

// ---------------- K4: pf_sp = spf1n@Q1 + spf2n@Q2 ----------------
// Proven R4-era shape: 128 thr, 2 px/thread float2, LDS-staged spf
// (linear copy since SPFN is [s][c]), A/B named prefetch.
#define P2STEP(V1, V2, s) { \
    _Pragma("unroll") for (int g = 0; g < 4; ++g) { \
        float4 s1 = *(const float4*)&spl[(0 * SS + (s)) * CC + g * 4]; \
        float4 s2 = *(const float4*)&spl[(SS + (s)) * CC + g * 4]; \
        acc[g*4+0].x += s1.x*V1.x + s2.x*V2.x; \
        acc[g*4+0].y += s1.x*V1.y + s2.x*V2.y; \
        acc[g*4+1].x += s1.y*V1.x + s2.y*V2.x; \
        acc[g*4+1].y += s1.y*V1.y + s2.y*V2.y; \
        acc[g*4+2].x += s1.z*V1.x + s2.z*V2.x; \
        acc[g*4+2].y += s1.z*V1.y + s2.z*V2.y; \
        acc[g*4+3].x += s1.w*V1.x + s2.w*V2.x; \
        acc[g*4+3].y += s1.w*V1.y + s2.w*V2.y; } }

__global__ __launch_bounds__(128) void k_pass2(const float* __restrict__ Q1,
                                               const float* __restrict__ Q2,
                                               float* __restrict__ ws) {
    int blk = blockIdx.x;   // 0..255
    int b   = blockIdx.y;
    __shared__ float spl[2 * SS * CC];
    int tid = threadIdx.x;
    const float* spin = ws + SPFN_OFF + (size_t)b * 2 * SS * CC;
    for (int idx = tid; idx < 2 * SS * CC; idx += 128) spl[idx] = spin[idx];
    __syncthreads();
    int n = blk * 256 + tid * 2;
    const float* q1p = Q1 + (size_t)b * SS * NN + n;
    const float* q2p = Q2 + (size_t)b * SS * NN + n;
    float2 acc[CC];
    #pragma unroll
    for (int c = 0; c < CC; ++c) acc[c] = make_float2(0.f, 0.f);
    float2 A1, A2, B1, B2;
    A1 = *(const float2*)(q1p);
    A2 = *(const float2*)(q2p);
    #pragma unroll 2
    for (int s = 0; s < 98; s += 2) {
        B1 = *(const float2*)(q1p + (size_t)(s + 1) * NN);
        B2 = *(const float2*)(q2p + (size_t)(s + 1) * NN);
        P2STEP(A1, A2, s)
        A1 = *(const float2*)(q1p + (size_t)(s + 2) * NN);
        A2 = *(const float2*)(q2p + (size_t)(s + 2) * NN);
        P2STEP(B1, B2, s + 1)
    }
    B1 = *(const float2*)(q1p + (size_t)99 * NN);
    B2 = *(const float2*)(q2p + (size_t)99 * NN);
    P2STEP(A1, A2, 98)
    P2STEP(B1, B2, 99)
    float* o = ws + PFSP_OFF + (size_t)b * CC * NN + n;
    #pragma unroll
    for (int c = 0; c < CC; ++c)
        *(float2*)(o + (size_t)c * NN) = acc[c];
}

// ---------------- K5: 3x3 conv, 16 -> 2 channels, + bias ----------------
__global__ __launch_bounds__(256) void k_conv(const float* __restrict__ w_ds,
                                              const float* __restrict__ b_ds,
                                              const float* __restrict__ ws,
                                              float* __restrict__ out) {
    int b = blockIdx.y;
    int n = blockIdx.x * 256 + threadIdx.x;
    __shared__ float wl[2][CC][9];
    __shared__ float bl[2];
    for (int i = threadIdx.x; i < 2 * CC * 9; i += 256)
        ((float*)wl)[i] = w_ds[i];
    if (threadIdx.x < 2) bl[threadIdx.x] = b_ds[threadIdx.x];
    __syncthreads();
    int y = n >> 8, x = n & 255;
    const float* base = ws + PFSP_OFF + (size_t)b * CC * NN;
    float a0 = bl[0], a1 = bl[1];
    for (int c = 0; c < CC; ++c) {
        const float* pc = base + (size_t)c * NN;
        #pragma unroll
        for (int dy = -1; dy <= 1; ++dy) {
            int yy = y + dy;
            if (yy < 0 || yy >= HH) continue;
            #pragma unroll
            for (int dx = -1; dx <= 1; ++dx) {
                int xx = x + dx;
                if (xx < 0 || xx >= WW) continue;
                float v = pc[(size_t)yy * WW + xx];
                int k = (dy + 1) * 3 + (dx + 1);
                a0 += v * wl[0][c][k];
                a1 += v * wl[1][c][k];
            }
        }
    }
    out[((size_t)b * 2 + 0) * NN + n] = a0;
    out[((size_t)b * 2 + 1) * NN + n] = a1;
}

extern "C" void kernel_launch(void* const* d_in, const int* in_sizes, int n_in,
                              void* d_out, int out_size, void* d_ws, size_t ws_size,
                              hipStream_t stream) {
    const float* pf   = (const float*)d_in[0];
    const float* spf1 = (const float*)d_in[1];
    const float* spf2 = (const float*)d_in[2];
    const float* Q1   = (const float*)d_in[3];
    const float* Q2   = (const float*)d_in[4];
    const float* w_ds = (const float*)d_in[5];
    const float* b_ds = (const float*)d_in[6];
    float* ws  = (float*)d_ws;
    float* out = (float*)d_out;

    k_pass1<<<dim3(128, 5, 8), 256, 0, stream>>>(pf, Q1, Q2, ws);
    k_reduceP<<<dim3(14, 8), 256, 0, stream>>>(ws);
    k_finalize<<<dim3(4, 8), 256, 0, stream>>>(spf1, spf2, ws);
    k_pass2<<<dim3(256, BB), 128, 0, stream>>>(Q1, Q2, ws);
    k_conv<<<dim3(NN / 256, BB), 256, 0, stream>>>(w_ds, b_ds, ws, out);
}

// Round 17
// 143.496 us; speedup vs baseline: 1.2841x; 1.1112x over previous
//
#include <hip/hip_runtime.h>

// Problem constants
#define BB 4
#define CC 16
#define HH 256
#define WW 256
#define NN (HH*WW)      // 65536
#define SS 100
#define EPSV 1e-32f

// ws layout (float offsets)
#define PQ_OFF    0u                      // [8 bq][100 s][2 row][17]      = 27200
#define SPFN_OFF  27200u                  // [8 bq][100 s][16 c]           = 12800
#define PFSP_OFF  40000u                  // [4][16][65536]                = 4194304
#define PPART_OFF PFSP_OFF                // [8][128 win][100 s][2 row][17]= 3481600
// PPART aliases PFSP: consumed by k_reduceP before k_pass2 overwrites.

typedef __fp16 h2 __attribute__((ext_vector_type(2)));

__device__ __forceinline__ float sum4(const float4& a) {
    return a.x + a.y + a.z + a.w;
}
__device__ __forceinline__ h2 as_h2(float f) {
    union { float f; h2 h; } u; u.f = f; return u.h;
}

#if __has_builtin(__builtin_amdgcn_fdot2)
__device__ __forceinline__ float fdot2(h2 a, h2 b, float c) {
    return __builtin_amdgcn_fdot2(a, b, c, false);
}
#else
__device__ __forceinline__ float fdot2(h2 a, h2 b, float c) {
    return c + (float)a.x * (float)b.x + (float)a.y * (float)b.y;
}
#endif

// DPP lane-combine. Uniform control flow only (R9 lesson).
#define DPPQP(x, ctrl) __int_as_float(__builtin_amdgcn_update_dpp( \
    0, __float_as_int(x), ctrl, 0xF, 0xF, true))
// 0xB1 qp xor1; 0x4E qp xor2; 0x111/0x112/0x114/0x118 row_shr 1/2/4/8

// ---------------- pass1 (K1) ----------------
// ZERO issued-byte amplification: pf staged ONCE per block in LDS (f16,
// 16KB), each wave owns ALL 16 channels x 512-px window x private 25-s
// slice -> every Q byte and pf byte issued to the memory system exactly
// once. Per s: 2 Q float4 loads, cvt to half2, 16 ds_read_b128 (pf),
// 64 fdot2, merge 16->4 stripes (xor1/xor2 DPP + sel), row_shr4+8,
// shfl_xor16 -> [2 row-pair][17] partial stores (R15 layout, downstream
// kernels unchanged). qsum from f32 Q (exact).
#define P1_STEP(QA, QB, sidx) { \
    float qv = sum4(QA) + sum4(QB); \
    h2 hq0 = __builtin_amdgcn_cvt_pkrtz(QA.x, QA.y); \
    h2 hq1 = __builtin_amdgcn_cvt_pkrtz(QA.z, QA.w); \
    h2 hq2 = __builtin_amdgcn_cvt_pkrtz(QB.x, QB.y); \
    h2 hq3 = __builtin_amdgcn_cvt_pkrtz(QB.z, QB.w); \
    float t0, t1, t2, t3, t4, t5, t6, t7, t8, t9, t10, t11, t12, t13, t14, t15; \
    P1_DOT(t0, 0)  P1_DOT(t1, 1)  P1_DOT(t2, 2)  P1_DOT(t3, 3) \
    P1_DOT(t4, 4)  P1_DOT(t5, 5)  P1_DOT(t6, 6)  P1_DOT(t7, 7) \
    P1_DOT(t8, 8)  P1_DOT(t9, 9)  P1_DOT(t10, 10) P1_DOT(t11, 11) \
    P1_DOT(t12, 12) P1_DOT(t13, 13) P1_DOT(t14, 14) P1_DOT(t15, 15) \
    t0 += DPPQP(t0,0xB1);   t1 += DPPQP(t1,0xB1); \
    t2 += DPPQP(t2,0xB1);   t3 += DPPQP(t3,0xB1); \
    t4 += DPPQP(t4,0xB1);   t5 += DPPQP(t5,0xB1); \
    t6 += DPPQP(t6,0xB1);   t7 += DPPQP(t7,0xB1); \
    t8 += DPPQP(t8,0xB1);   t9 += DPPQP(t9,0xB1); \
    t10 += DPPQP(t10,0xB1); t11 += DPPQP(t11,0xB1); \
    t12 += DPPQP(t12,0xB1); t13 += DPPQP(t13,0xB1); \
    t14 += DPPQP(t14,0xB1); t15 += DPPQP(t15,0xB1); \
    float v0 = odd ? t1 : t0;   float v1 = odd ? t3 : t2; \
    float v2 = odd ? t5 : t4;   float v3 = odd ? t7 : t6; \
    float v4 = odd ? t9 : t8;   float v5 = odd ? t11 : t10; \
    float v6 = odd ? t13 : t12; float v7 = odd ? t15 : t14; \
    v0 += DPPQP(v0,0x4E); v1 += DPPQP(v1,0x4E); \
    v2 += DPPQP(v2,0x4E); v3 += DPPQP(v3,0x4E); \
    v4 += DPPQP(v4,0x4E); v5 += DPPQP(v5,0x4E); \
    v6 += DPPQP(v6,0x4E); v7 += DPPQP(v7,0x4E); \
    float w0 = hi2 ? v1 : v0; float w1 = hi2 ? v3 : v2; \
    float w2 = hi2 ? v5 : v4; float w3 = hi2 ? v7 : v6; \
    w0 += DPPQP(w0,0x114); w1 += DPPQP(w1,0x114); \
    w2 += DPPQP(w2,0x114); w3 += DPPQP(w3,0x114); \
    w0 += DPPQP(w0,0x118); w1 += DPPQP(w1,0x118); \
    w2 += DPPQP(w2,0x118); w3 += DPPQP(w3,0x118); \
    w0 += __shfl_xor(w0,16); w1 += __shfl_xor(w1,16); \
    w2 += __shfl_xor(w2,16); w3 += __shfl_xor(w3,16); \
    qv += DPPQP(qv,0x111); qv += DPPQP(qv,0x112); \
    qv += DPPQP(qv,0x114); qv += DPPQP(qv,0x118); \
    qv += __shfl_xor(qv,16); \
    if ((lane & 15) >= 12 && !(lane & 16)) { \
        float* o = sout + (size_t)(sidx)*34 + (lane>>5)*17 + (lane & 3); \
        o[0] = w0; o[4] = w1; o[8] = w2; o[12] = w3; \
    } \
    if ((lane & 31) == 15) \
        sout[(size_t)(sidx)*34 + (lane>>5)*17 + 16] = qv; \
}

// lane's pf for channel c: one ds_read_b128 -> 4 half2
#define P1_DOT(dst, c) { \
    float4 rc = *(const float4*)&pfl[c][lane][0]; \
    dst = fdot2(as_h2(rc.x), hq0, \
          fdot2(as_h2(rc.y), hq1, \
          fdot2(as_h2(rc.z), hq2, \
          fdot2(as_h2(rc.w), hq3, 0.f)))); \
}

__global__ __launch_bounds__(256) void k_pass1(const float* __restrict__ pf,
                                               const float* __restrict__ Q1,
                                               const float* __restrict__ Q2,
                                               float* __restrict__ ws) {
    int tid = threadIdx.x, wid = tid >> 6, lane = tid & 63;
    int win = blockIdx.x;      // 0..127 (512-px window)
    int bq  = blockIdx.y;      // 0..7
    int b = bq >> 1, q = bq & 1;
    bool odd = lane & 1;
    bool hi2 = lane & 2;

    __shared__ __align__(16) __fp16 pfl[CC][64][8];   // 16 KB

    const float* PF = pf + (size_t)b * CC * NN + win * 512;
    // stage pf window -> LDS f16. lane layout: pfl[c][l][0..3] = px l*4..,
    // [4..7] = px 256+l*4..
    for (int i = 0; i < 8; ++i) {
        int slot = i * 256 + tid;
        int c = slot >> 7, pos = slot & 127;
        float4 v = *(const float4*)(PF + (size_t)c * NN + pos * 4);
        int l = pos & 63, hh = pos >> 6;
        h2 a = __builtin_amdgcn_cvt_pkrtz(v.x, v.y);
        h2 b2 = __builtin_amdgcn_cvt_pkrtz(v.z, v.w);
        h2* dst = (h2*)&pfl[c][l][hh * 4];
        dst[0] = a; dst[1] = b2;
    }
    __syncthreads();

    // wave w owns s in [w*25, w*25+25)
    const float* qptr = (q ? Q2 : Q1) + (size_t)b * SS * NN
                        + (size_t)(wid * 25) * NN + win * 512 + lane * 4;
    float* sout = ws + PPART_OFF
                + (size_t)((bq * 128 + win) * 100 + wid * 25) * 34;

    float4 Aa, Ab, Ba, Bb;
    Aa = *(const float4*)(qptr);
    Ab = *(const float4*)(qptr + 256);
    #pragma unroll 2
    for (int i = 0; i < 12; ++i) {
        Ba = *(const float4*)(qptr + (size_t)(2 * i + 1) * NN);
        Bb = *(const float4*)(qptr + (size_t)(2 * i + 1) * NN + 256);
        P1_STEP(Aa, Ab, 2 * i)
        Aa = *(const float4*)(qptr + (size_t)(2 * i + 2) * NN);
        Ab = *(const float4*)(qptr + (size_t)(2 * i + 2) * NN + 256);
        P1_STEP(Ba, Bb, 2 * i + 1)
    }
    P1_STEP(Aa, Ab, 24)
}

// ---------------- K2: reduce over 128 windows (coalesced) ----------------
__global__ __launch_bounds__(256) void k_reduceP(float* __restrict__ ws) {
    int strip = blockIdx.x;  // 0..13
    int bq    = blockIdx.y;  // 0..7
    int idx = strip * 256 + threadIdx.x;
    if (idx < 3400) {
        const float* pp = ws + PPART_OFF + (size_t)bq * 128 * 3400 + idx;
        float a0 = 0.f, a1 = 0.f;
        #pragma unroll 4
        for (int win = 0; win < 128; win += 2) {
            a0 += pp[(size_t)win * 3400];
            a1 += pp[(size_t)(win + 1) * 3400];
        }
        ws[PQ_OFF + (size_t)bq * 3400 + idx] = a0 + a1;
    }
}

// ---------------- K3: rels + finalize (s-quarter split) ----------------
__global__ __launch_bounds__(256) void k_finalize(const float* __restrict__ spf1,
                                                  const float* __restrict__ spf2,
                                                  float* __restrict__ ws) {
    int sq = blockIdx.x;  // 0..3 (25 s each)
    int bq = blockIdx.y;  // 0..7
    int b = bq >> 1, q = bq & 1;
    __shared__ float sp[CC][SS];
    __shared__ float rl[25][SS + 1];
    __shared__ float Pl[CC * SS];
    __shared__ float qs[SS];
    __shared__ float den[25];
    int tid = threadIdx.x;

    const float* spf = (q ? spf2 : spf1) + (size_t)b * CC * SS;
    for (int i = tid; i < CC * SS; i += 256) sp[i / SS][i % SS] = spf[i];
    const float* pq = ws + PQ_OFF + (size_t)bq * 3400;
    for (int idx = tid; idx < CC * SS; idx += 256) {
        int c = idx / SS, t = idx % SS;
        Pl[idx] = pq[(size_t)t * 34 + c] + pq[(size_t)t * 34 + 17 + c];
    }
    if (tid < SS) qs[tid] = pq[(size_t)tid * 34 + 16] + pq[(size_t)tid * 34 + 33];
    __syncthreads();
    for (int i = tid; i < 25 * SS; i += 256) {
        int sl = i / SS, t = i % SS;
        int s = sq * 25 + sl;
        float d2 = 0.f;
        #pragma unroll
        for (int c = 0; c < CC; ++c) {
            float d = sp[c][t] - sp[c][s];
            d2 += d * d;
        }
        rl[sl][t] = expf(-d2);
    }
    __syncthreads();
    if (tid < 25) {
        float a = 0.f;
        for (int t = 0; t < SS; ++t) a += rl[tid][t] * qs[t];
        den[tid] = a + EPSV;
    }
    __syncthreads();
    float* sout = ws + SPFN_OFF + (size_t)bq * SS * CC;
    for (int idx = tid; idx < 25 * CC; idx += 256) {
        int sl = idx / CC, c = idx % CC;
        float a = 0.f;
        for (int t = 0; t < SS; ++t) a += rl[sl][t] * Pl[c * SS + t];
        sout[(size_t)(sq * 25 + sl) * CC + c] = a / den[sl];
    }
}

// ---------------- K4: pf_sp = spf1n@Q1 + spf2n@Q2 ----------------
#define P2STEP(V1, V2, s) { \
    _Pragma("unroll") for (int g = 0; g < 4; ++g) { \
        float4 s1 = *(const float4*)&spl[(0 * SS + (s)) * CC + g * 4]; \
        float4 s2 = *(const float4*)&spl[(SS + (s)) * CC + g * 4]; \
        acc[g*4+0].x += s1.x*V1.x + s2.x*V2.x; \
        acc[g*4+0].y += s1.x*V1.y + s2.x*V2.y; \
        acc[g*4+1].x += s1.y*V1.x + s2.y*V2.x; \
        acc[g*4+1].y += s1.y*V1.y + s2.y*V2.y; \
        acc[g*4+2].x += s1.z*V1.x + s2.z*V2.x; \
        acc[g*4+2].y += s1.z*V1.y + s2.z*V2.y; \
        acc[g*4+3].x += s1.w*V1.x + s2.w*V2.x; \
        acc[g*4+3].y += s1.w*V1.y + s2.w*V2.y; } }

__global__ __launch_bounds__(128) void k_pass2(const float* __restrict__ Q1,
                                               const float* __restrict__ Q2,
                                               float* __restrict__ ws) {
    int blk = blockIdx.x;   // 0..255
    int b   = blockIdx.y;
    __shared__ float spl[2 * SS * CC];
    int tid = threadIdx.x;
    const float* spin = ws + SPFN_OFF + (size_t)b * 2 * SS * CC;
    for (int idx = tid; idx < 2 * SS * CC; idx += 128) spl[idx] = spin[idx];
    __syncthreads();
    int n = blk * 256 + tid * 2;
    const float* q1p = Q1 + (size_t)b * SS * NN + n;
    const float* q2p = Q2 + (size_t)b * SS * NN + n;
    float2 acc[CC];
    #pragma unroll
    for (int c = 0; c < CC; ++c) acc[c] = make_float2(0.f, 0.f);
    float2 A1, A2, B1, B2;
    A1 = *(const float2*)(q1p);
    A2 = *(const float2*)(q2p);
    #pragma unroll 2
    for (int s = 0; s < 98; s += 2) {
        B1 = *(const float2*)(q1p + (size_t)(s + 1) * NN);
        B2 = *(const float2*)(q2p + (size_t)(s + 1) * NN);
        P2STEP(A1, A2, s)
        A1 = *(const float2*)(q1p + (size_t)(s + 2) * NN);
        A2 = *(const float2*)(q2p + (size_t)(s + 2) * NN);
        P2STEP(B1, B2, s + 1)
    }
    B1 = *(const float2*)(q1p + (size_t)99 * NN);
    B2 = *(const float2*)(q2p + (size_t)99 * NN);
    P2STEP(A1, A2, 98)
    P2STEP(B1, B2, 99)
    float* o = ws + PFSP_OFF + (size_t)b * CC * NN + n;
    #pragma unroll
    for (int c = 0; c < CC; ++c)
        *(float2*)(o + (size_t)c * NN) = acc[c];
}

// ---------------- K5: 3x3 conv, 16 -> 2 channels, + bias ----------------
__global__ __launch_bounds__(256) void k_conv(const float* __restrict__ w_ds,
                                              const float* __restrict__ b_ds,
                                              const float* __restrict__ ws,
                                              float* __restrict__ out) {
    int b = blockIdx.y;
    int n = blockIdx.x * 256 + threadIdx.x;
    __shared__ float wl[2][CC][9];
    __shared__ float bl[2];
    for (int i = threadIdx.x; i < 2 * CC * 9; i += 256)
        ((float*)wl)[i] = w_ds[i];
    if (threadIdx.x < 2) bl[threadIdx.x] = b_ds[threadIdx.x];
    __syncthreads();
    int y = n >> 8, x = n & 255;
    const float* base = ws + PFSP_OFF + (size_t)b * CC * NN;
    float a0 = bl[0], a1 = bl[1];
    for (int c = 0; c < CC; ++c) {
        const float* pc = base + (size_t)c * NN;
        #pragma unroll
        for (int dy = -1; dy <= 1; ++dy) {
            int yy = y + dy;
            if (yy < 0 || yy >= HH) continue;
            #pragma unroll
            for (int dx = -1; dx <= 1; ++dx) {
                int xx = x + dx;
                if (xx < 0 || xx >= WW) continue;
                float v = pc[(size_t)yy * WW + xx];
                int k = (dy + 1) * 3 + (dx + 1);
                a0 += v * wl[0][c][k];
                a1 += v * wl[1][c][k];
            }
        }
    }
    out[((size_t)b * 2 + 0) * NN + n] = a0;
    out[((size_t)b * 2 + 1) * NN + n] = a1;
}

extern "C" void kernel_launch(void* const* d_in, const int* in_sizes, int n_in,
                              void* d_out, int out_size, void* d_ws, size_t ws_size,
                              hipStream_t stream) {
    const float* pf   = (const float*)d_in[0];
    const float* spf1 = (const float*)d_in[1];
    const float* spf2 = (const float*)d_in[2];
    const float* Q1   = (const float*)d_in[3];
    const float* Q2   = (const float*)d_in[4];
    const float* w_ds = (const float*)d_in[5];
    const float* b_ds = (const float*)d_in[6];
    float* ws  = (float*)d_ws;
    float* out = (float*)d_out;

    k_pass1<<<dim3(128, 8), 256, 0, stream>>>(pf, Q1, Q2, ws);
    k_reduceP<<<dim3(14, 8), 256, 0, stream>>>(ws);
    k_finalize<<<dim3(4, 8), 256, 0, stream>>>(spf1, spf2, ws);
    k_pass2<<<dim3(256, BB), 128, 0, stream>>>(Q1, Q2, ws);
    k_conv<<<dim3(NN / 256, BB), 256, 0, stream>>>(w_ds, b_ds, ws, out);
}